// Round 10
// baseline (8342.071 us; speedup 1.0000x reference)
//
#include <hip/hip_runtime.h>
#include <math.h>

#define BB 128
#define TT 256
#define DD 512
#define HH 1024
#define G4H 4096
#define CO 7
#define XROW (TT * DD)      // x row stride per batch (fp32 elements)
#define LOOFF (BB * HH)     // offset of lo-plane within an h slot (elements)

typedef __attribute__((ext_vector_type(8))) short bf16x8;
typedef __attribute__((ext_vector_type(4))) float f32x4;

__device__ __forceinline__ unsigned short f2bf(float f) {
  unsigned int u = __float_as_uint(f);
  unsigned int r = (u + 0x7fffu + ((u >> 16) & 1u)) >> 16;
  return (unsigned short)r;
}
__device__ __forceinline__ float bf2f(unsigned short h) {
  return __uint_as_float(((unsigned int)h) << 16);
}
__device__ __forceinline__ float tanh_fast(float x) {
  x = fminf(fmaxf(x, -15.f), 15.f);
  const float e = __expf(2.f * x);
  return (e - 1.f) / (e + 1.f);
}
__device__ __forceinline__ float sigmoid_fast(float x) {
  return 1.f / (1.f + __expf(-x));
}
__device__ __forceinline__ void split8(float4 a, float4 b, bf16x8& hi, bf16x8& lo) {
  float f[8] = {a.x, a.y, a.z, a.w, b.x, b.y, b.z, b.w};
  unsigned short h8[8], l8[8];
#pragma unroll
  for (int e = 0; e < 8; ++e) {
    const unsigned short hh = f2bf(f[e]);
    h8[e] = hh;
    l8[e] = f2bf(f[e] - bf2f(hh));
  }
  hi = *(bf16x8*)h8;
  lo = *(bf16x8*)l8;
}

// ------------------------------------------------------------------
// Pack concatenated weights [Wh | Wx] into fragment-major bf16 hi/lo,
// gate-interleaved n-permutation: srow(n) = (n&3)*1024 + (n>>6)*16 + ((n>>2)&15)
// pk[((nt*KS + ks)*2 + hilo)*512 + l*8 + e] = src[srow(nt*16+(l&15))][ks*32+(l>>4)*8+e]
// ------------------------------------------------------------------
__global__ __launch_bounds__(256)
void pack_w2(const float* __restrict__ Wh, const float* __restrict__ Wx,
             unsigned short* __restrict__ pk, int Kh, int Kx) {
  const int KS = (Kh + Kx) >> 5;
  const int idx = blockIdx.x * 256 + threadIdx.x;
  const int total = 256 * KS * 64;
  if (idx >= total) return;
  const int l = idx & 63;
  const int t2 = idx >> 6;
  const int ks = t2 % KS;
  const int nt = t2 / KS;
  const int n = (nt << 4) + (l & 15);
  const int srow = ((n & 3) << 10) + ((n >> 6) << 4) + ((n >> 2) & 15);
  const int col = (ks << 5) + ((l >> 4) << 3);
  const float* src = (col < Kh) ? (Wh + (size_t)srow * Kh + col)
                                : (Wx + (size_t)srow * Kx + (col - Kh));
  unsigned short hi[8], lo[8];
#pragma unroll
  for (int e = 0; e < 8; ++e) {
    const float v = src[e];
    const unsigned short h = f2bf(v);
    hi[e] = h;
    lo[e] = f2bf(v - bf2f(h));
  }
  const size_t base = (((size_t)nt * KS + ks) * 2) * 512 + (size_t)l * 8;
  *(uint4*)(pk + base) = *(const uint4*)hi;
  *(uint4*)(pk + base + 512) = *(const uint4*)lo;
}

// LDS buffer layout (40960 B used per buffer; padded to 49152 to pin 1 WG/CU):
//  [0, 8192):      W block (2 nt x 64 K): nt_l*4096 + ksl*2048 + hilo*1024 + l*16
//  [8192, 24576):  A hi bf16: row*128 + ((unit16 ^ (row&7))<<4)   (128 rows x 64 K)
//  [24576, 40960): A lo bf16 (same addressing)

// ------------------------------------------------------------------
// Diagonal dual-layer step, W-dedup'd: WGs 0..127 = layer0 @ t, WGs 128..255
// = layer1 @ t-1. WG q owns 32 perm-cols (nt = 2q, 2q+1) x ALL 128 rows ->
// every W byte read exactly once per dispatch. 8 waves = 4 row-quarters x
// 2 col-tiles, full K per wave (no K-split reduction).
// ------------------------------------------------------------------
__global__ __launch_bounds__(512, 1)
void step_dual(int t,
               const float* __restrict__ x,
               const unsigned short* __restrict__ pk0,
               const unsigned short* __restrict__ pk1,
               unsigned short* __restrict__ h0s0, unsigned short* __restrict__ h0s1,
               unsigned short* __restrict__ h1s0, unsigned short* __restrict__ h1s1,
               const float* __restrict__ bih0, const float* __restrict__ bhh0,
               const float* __restrict__ bih1, const float* __restrict__ bhh1,
               float* __restrict__ c0, float* __restrict__ c1) {
  __shared__ __align__(16) char lds0[49152];
  __shared__ __align__(16) char lds1[49152];
  const int bid = blockIdx.x;
  const int layer = bid >> 7;
  if (layer == 0 && t >= TT) return;
  if (layer == 1 && t < 1) return;
  const int q = bid & 127;
  const int tid = threadIdx.x;
  const int wid = tid >> 6, l = tid & 63;
  const int rq = wid >> 1, ch = wid & 1;   // row-quarter 0..3, col-tile 0..1
  const int l15 = l & 15, l4 = l >> 4;

  // per-layer configuration
  const int KS = layer ? 64 : 48;     // K in 32-unit slices
  const int NB = layer ? 32 : 24;     // 64-K blocks
  const unsigned short* pk = layer ? pk1 : pk0;
  const unsigned short* a1;           // prev-h of own layer (hi base; lo at +LOOFF)
  const unsigned short* a2;           // layer1: h0[t-1]
  unsigned short* ho;
  float* cb;
  const float* bv0;
  const float* bv1;
  if (layer == 0) {
    a1 = (t & 1) ? h0s0 : h0s1;
    ho = (t & 1) ? h0s1 : h0s0;
    a2 = a1;
    cb = c0; bv0 = bih0; bv1 = bhh0;
  } else {
    const int u = t - 1;
    a1 = (u & 1) ? h1s0 : h1s1;
    ho = (u & 1) ? h1s1 : h1s0;
    a2 = (t & 1) ? h0s0 : h0s1;
    cb = c1; bv0 = bih1; bv1 = bhh1;
  }

  // ---- staging maps ----
  // A: thread = (arow 0..127, aseg 0..3); each stages 16 k-elems (units 2*aseg, 2*aseg+1)
  const int arow = tid >> 2;
  const int aseg = tid & 3;
  const int r7w = arow & 7;
  const unsigned short* a1g = a1 + (size_t)arow * HH;
  const unsigned short* a2g = a2 + (size_t)arow * HH;
  const float* xg = x + (size_t)t * DD + (size_t)arow * XROW;
  const int aw0 = 8192 + arow * 128 + ((((aseg << 1) + 0) ^ r7w) << 4);
  const int aw1 = 8192 + arow * 128 + ((((aseg << 1) + 1) ^ r7w) << 4);

  // W: thread = (w_nt, w_ks, w_hl, l_w); 1 uint4 each, LDS-linear at tid*16
  const int w_nt = tid >> 8;
  const int w_ks = (tid >> 7) & 1;
  const int w_hl = (tid >> 6) & 1;
  const int l_w = tid & 63;
  const unsigned short* pkg = pk + (((size_t)((q << 1) + w_nt) * KS + w_ks) * 2
                                    + w_hl) * 512 + (size_t)l_w * 8;
  // per-block advance = 2 ks-slices = 2048 elems

  // ---- read offsets ----
  const int wrb = ch * 4096 + l * 16;            // + ksl*2048 (+1024 for lo)
  const int row0 = (rq << 5) + l15;              // tile0 row
  const int arb0 = 8192 + row0 * 128;
  const int arb1 = arb0 + 16 * 128;              // tile1 (+16 rows: same row&7)
  const int r7r = row0 & 7;

  f32x4 acc0 = (f32x4)(0.f), acc1 = (f32x4)(0.f);
  uint4 qw, qa0, qa1, qa2, qa3;

#define LOADW(bb) do { qw = *(const uint4*)(pkg + (size_t)(bb) * 2048); } while (0)

#define LOADA(bb) do {                                                          \
    if ((bb) < 16) {                                                            \
      const unsigned short* s_ = a1g + ((bb) << 6) + (aseg << 4);               \
      qa0 = *(const uint4*)s_;           qa1 = *(const uint4*)(s_ + 8);         \
      qa2 = *(const uint4*)(s_ + LOOFF); qa3 = *(const uint4*)(s_ + LOOFF + 8); \
    } else if (layer == 1) {                                                    \
      const unsigned short* s_ = a2g + (((bb) - 16) << 6) + (aseg << 4);        \
      qa0 = *(const uint4*)s_;           qa1 = *(const uint4*)(s_ + 8);         \
      qa2 = *(const uint4*)(s_ + LOOFF); qa3 = *(const uint4*)(s_ + LOOFF + 8); \
    } else {                                                                    \
      const float* s_ = xg + (((bb) - 16) << 6) + (aseg << 4);                  \
      qa0 = *(const uint4*)s_;       qa1 = *(const uint4*)(s_ + 4);             \
      qa2 = *(const uint4*)(s_ + 8); qa3 = *(const uint4*)(s_ + 12);            \
    }                                                                           \
  } while (0)

#define WRITEB(buf, bb) do {                                                    \
    *(uint4*)((buf) + tid * 16) = qw;                                           \
    if ((bb) < 16 || layer == 1) {                                              \
      *(uint4*)((buf) + aw0) = qa0; *(uint4*)((buf) + aw1) = qa1;               \
      *(uint4*)((buf) + aw0 + 16384) = qa2; *(uint4*)((buf) + aw1 + 16384) = qa3; \
    } else {                                                                    \
      bf16x8 xh0, xl0, xh1, xl1;                                                \
      split8(*(float4*)&qa0, *(float4*)&qa1, xh0, xl0);                         \
      split8(*(float4*)&qa2, *(float4*)&qa3, xh1, xl1);                         \
      *(bf16x8*)((buf) + aw0) = xh0; *(bf16x8*)((buf) + aw1) = xh1;             \
      *(bf16x8*)((buf) + aw0 + 16384) = xl0; *(bf16x8*)((buf) + aw1 + 16384) = xl1; \
    }                                                                           \
  } while (0)

#define COMPB(buf) do {                                                         \
    _Pragma("unroll")                                                           \
    for (int ksl = 0; ksl < 2; ++ksl) {                                         \
      const bf16x8 wh = *(const bf16x8*)((buf) + wrb + ksl * 2048);             \
      const bf16x8 wl = *(const bf16x8*)((buf) + wrb + ksl * 2048 + 1024);      \
      const int so = ((((ksl << 2) + l4) ^ r7r) << 4);                          \
      const bf16x8 ah0 = *(const bf16x8*)((buf) + arb0 + so);                   \
      const bf16x8 al0 = *(const bf16x8*)((buf) + arb0 + so + 16384);           \
      const bf16x8 ah1 = *(const bf16x8*)((buf) + arb1 + so);                   \
      const bf16x8 al1 = *(const bf16x8*)((buf) + arb1 + so + 16384);           \
      acc0 = __builtin_amdgcn_mfma_f32_16x16x32_bf16(ah0, wh, acc0, 0, 0, 0);   \
      acc0 = __builtin_amdgcn_mfma_f32_16x16x32_bf16(ah0, wl, acc0, 0, 0, 0);   \
      acc0 = __builtin_amdgcn_mfma_f32_16x16x32_bf16(al0, wh, acc0, 0, 0, 0);   \
      acc1 = __builtin_amdgcn_mfma_f32_16x16x32_bf16(ah1, wh, acc1, 0, 0, 0);   \
      acc1 = __builtin_amdgcn_mfma_f32_16x16x32_bf16(ah1, wl, acc1, 0, 0, 0);   \
      acc1 = __builtin_amdgcn_mfma_f32_16x16x32_bf16(al1, wh, acc1, 0, 0, 0);   \
    }                                                                           \
  } while (0)

  // prologue: stage block 0
  LOADW(0); LOADA(0);
  WRITEB(lds0, 0);
  __syncthreads();

  for (int b = 0; b < NB; ++b) {
    char* cur = (b & 1) ? lds1 : lds0;
    char* nxt = (b & 1) ? lds0 : lds1;
    if (b + 1 < NB) { LOADW(b + 1); LOADA(b + 1); }
    COMPB(cur);
    if (b + 1 < NB) WRITEB(nxt, b + 1);
    __syncthreads();
  }
#undef LOADW
#undef LOADA
#undef WRITEB
#undef COMPB

  // epilogue: bias + cell + h store (quad shfl gather over l15&3)
  const int n = (((q << 1) + ch) << 4) + l15;
  const int srn = ((n & 3) << 10) + ((n >> 6) << 4) + ((n >> 2) & 15);
  const float bn = bv0[srn] + bv1[srn];
  const int g = l15 & 3;
  const int j = srn & 1023;
  f32x4 accs[2] = {acc0, acc1};
#pragma unroll
  for (int mt = 0; mt < 2; ++mt) {
#pragma unroll
    for (int r = 0; r < 4; ++r) {
      const float v = accs[mt][r] + bn;
      const float v1 = __shfl_xor(v, 1);
      const float v2 = __shfl_xor(v, 2);
      const float v3 = __shfl_xor(v, 3);
      if (g == 0) {
        const int row = (rq << 5) + (mt << 4) + (l4 << 2) + r;
        const float si = sigmoid_fast(v);
        const float sf = sigmoid_fast(v1);
        const float tg = tanh_fast(v2);
        const float so = sigmoid_fast(v3);
        const size_t ci = (size_t)row * HH + j;
        const float cn = sf * cb[ci] + si * tg;
        cb[ci] = cn;
        const float h = so * tanh_fast(cn);
        const unsigned short hh = f2bf(h);
        ho[(size_t)row * HH + j] = hh;
        ho[LOOFF + (size_t)row * HH + j] = f2bf(h - bf2f(hh));
      }
    }
  }
}

// ------------------------------------------------------------------
// FC from hi/lo h slot
// ------------------------------------------------------------------
__global__ __launch_bounds__(256)
void fc_hilo(const unsigned short* __restrict__ hhi, const unsigned short* __restrict__ hlo,
             const float* __restrict__ fcw, const float* __restrict__ fcb,
             float* __restrict__ out) {
  const int gw = (int)((blockIdx.x * 256 + threadIdx.x) >> 6);
  const int lane = threadIdx.x & 63;
  const int b = gw / CO;
  const int n = gw - b * CO;
  const unsigned short* hp = hhi + (size_t)b * HH;
  const unsigned short* lp = hlo + (size_t)b * HH;
  const float* wp = fcw + (size_t)n * HH;
  float s = 0.f;
  for (int k = lane; k < HH; k += 64) s += (bf2f(hp[k]) + bf2f(lp[k])) * wp[k];
#pragma unroll
  for (int off = 32; off; off >>= 1) s += __shfl_down(s, off);
  if (lane == 0) out[b * CO + n] = s + fcb[n];
}

// ==================================================================
// Fallback fp32 path (round-2 kernels, used only if ws_size is small)
// ==================================================================
__global__ __launch_bounds__(256)
void gemm_bias(const float* __restrict__ A, long long sOut, long long sIn, int lt,
               const float* __restrict__ W,
               const float* __restrict__ b0, const float* __restrict__ b1,
               float* __restrict__ C, int N, int K) {
  __shared__ float as[16][64];
  __shared__ float wsh[16][64];
  const int tid = threadIdx.x;
  const int bm = blockIdx.y << 6;
  const int bn = blockIdx.x << 6;
  const int tr = (tid >> 4) << 2;
  const int tc = (tid & 15) << 2;
  const int lrow = tid >> 2;
  const int lk4 = (tid & 3) << 2;
  const int msk = (1 << lt) - 1;
  const int r = bm + lrow;
  const float* ap = A + (size_t)(r >> lt) * sOut + (size_t)(r & msk) * sIn + lk4;
  const float* wp = W + (size_t)(bn + lrow) * K + lk4;
  float acc[4][4] = {};
  for (int k0 = 0; k0 < K; k0 += 16) {
    const float4 av = *(const float4*)(ap + k0);
    const float4 wv = *(const float4*)(wp + k0);
    __syncthreads();
    as[lk4 + 0][lrow] = av.x; as[lk4 + 1][lrow] = av.y;
    as[lk4 + 2][lrow] = av.z; as[lk4 + 3][lrow] = av.w;
    wsh[lk4 + 0][lrow] = wv.x; wsh[lk4 + 1][lrow] = wv.y;
    wsh[lk4 + 2][lrow] = wv.z; wsh[lk4 + 3][lrow] = wv.w;
    __syncthreads();
#pragma unroll
    for (int k = 0; k < 16; ++k) {
      const float4 a = *(const float4*)&as[k][tr];
      const float4 b = *(const float4*)&wsh[k][tc];
      acc[0][0] += a.x * b.x; acc[0][1] += a.x * b.y; acc[0][2] += a.x * b.z; acc[0][3] += a.x * b.w;
      acc[1][0] += a.y * b.x; acc[1][1] += a.y * b.y; acc[1][2] += a.y * b.z; acc[1][3] += a.y * b.w;
      acc[2][0] += a.z * b.x; acc[2][1] += a.z * b.y; acc[2][2] += a.z * b.z; acc[2][3] += a.z * b.w;
      acc[3][0] += a.w * b.x; acc[3][1] += a.w * b.y; acc[3][2] += a.w * b.z; acc[3][3] += a.w * b.w;
    }
  }
  const float* bp0 = b0 + bn + tc;
  const float* bp1 = b1 + bn + tc;
#pragma unroll
  for (int i = 0; i < 4; ++i) {
    float* cp = C + (size_t)(bm + tr + i) * N + bn + tc;
#pragma unroll
    for (int j = 0; j < 4; ++j) cp[j] = acc[i][j] + bp0[j] + bp1[j];
  }
}

__global__ __launch_bounds__(256)
void lstm_step(const float* __restrict__ gx, long long gxstride,
               const float* __restrict__ whh,
               const float* __restrict__ hprev, long long pstride,
               float* __restrict__ hnext, long long nstride,
               float* __restrict__ cbuf) {
  __shared__ float hs[32][16];
  __shared__ float wsm[32][4][32];
  const int tid = threadIdx.x;
  const int jt = blockIdx.x << 5;
  const int bm = blockIdx.y << 4;
  const int col = tid & 31;
  const int rp = (tid >> 5) << 1;
  const int hr = tid >> 4;
  const int hk = (tid & 15) << 1;
  const int wrow = tid & 127;
  const int wg = wrow >> 5;
  const int wc = wrow & 31;
  const int wk = (tid >> 7) << 4;
  const float* wbase = whh + (size_t)(wg * HH + jt + wc) * HH + wk;
  const float* hbase = hprev + (size_t)(bm + hr) * pstride + hk;

  float acc[4][2] = {};
  for (int k0 = 0; k0 < HH; k0 += 32) {
    const float2 hv = *(const float2*)(hbase + k0);
    const float4 wv0 = *(const float4*)(wbase + k0);
    const float4 wv1 = *(const float4*)(wbase + k0 + 4);
    const float4 wv2 = *(const float4*)(wbase + k0 + 8);
    const float4 wv3 = *(const float4*)(wbase + k0 + 12);
    __syncthreads();
    hs[hk][hr] = hv.x; hs[hk + 1][hr] = hv.y;
    {
      const float wvv[16] = {wv0.x, wv0.y, wv0.z, wv0.w, wv1.x, wv1.y, wv1.z, wv1.w,
                             wv2.x, wv2.y, wv2.z, wv2.w, wv3.x, wv3.y, wv3.z, wv3.w};
#pragma unroll
      for (int i = 0; i < 16; ++i) wsm[wk + i][wg][wc] = wvv[i];
    }
    __syncthreads();
#pragma unroll
    for (int k = 0; k < 32; ++k) {
      const float2 a = *(const float2*)&hs[k][rp];
      const float wi = wsm[k][0][col];
      const float wf = wsm[k][1][col];
      const float wg_ = wsm[k][2][col];
      const float wo = wsm[k][3][col];
      acc[0][0] += a.x * wi;  acc[0][1] += a.y * wi;
      acc[1][0] += a.x * wf;  acc[1][1] += a.y * wf;
      acc[2][0] += a.x * wg_; acc[2][1] += a.y * wg_;
      acc[3][0] += a.x * wo;  acc[3][1] += a.y * wo;
    }
  }
#pragma unroll
  for (int rr = 0; rr < 2; ++rr) {
    const int b = bm + rp + rr;
    const int j = jt + col;
    const size_t gxo = (size_t)b * gxstride + j;
    const float gi = acc[0][rr] + gx[gxo];
    const float gf = acc[1][rr] + gx[gxo + HH];
    const float gg = acc[2][rr] + gx[gxo + 2 * HH];
    const float go = acc[3][rr] + gx[gxo + 3 * HH];
    const float si = 1.f / (1.f + expf(-gi));
    const float sf = 1.f / (1.f + expf(-gf));
    const float so = 1.f / (1.f + expf(-go));
    const size_t cidx = (size_t)b * HH + j;
    const float cn = sf * cbuf[cidx] + si * tanhf(gg);
    cbuf[cidx] = cn;
    hnext[(size_t)b * nstride + j] = so * tanhf(cn);
  }
}

__global__ __launch_bounds__(256)
void fc_kernel(const float* __restrict__ hlast, const float* __restrict__ fcw,
               const float* __restrict__ fcb, float* __restrict__ out) {
  const int gw = (int)((blockIdx.x * 256 + threadIdx.x) >> 6);
  const int lane = threadIdx.x & 63;
  const int b = gw / CO;
  const int n = gw - b * CO;
  const float* hp = hlast + (size_t)b * HH;
  const float* wp = fcw + (size_t)n * HH;
  float s = 0.f;
  for (int k = lane; k < HH; k += 64) s += hp[k] * wp[k];
#pragma unroll
  for (int off = 32; off; off >>= 1) s += __shfl_down(s, off);
  if (lane == 0) out[b * CO + n] = s + fcb[n];
}

// ==================================================================
extern "C" void kernel_launch(void* const* d_in, const int* in_sizes, int n_in,
                              void* d_out, int out_size, void* d_ws, size_t ws_size,
                              hipStream_t stream) {
  const float* x    = (const float*)d_in[0];
  const float* wih0 = (const float*)d_in[1];
  const float* whh0 = (const float*)d_in[2];
  const float* bih0 = (const float*)d_in[3];
  const float* bhh0 = (const float*)d_in[4];
  const float* wih1 = (const float*)d_in[5];
  const float* whh1 = (const float*)d_in[6];
  const float* bih1 = (const float*)d_in[7];
  const float* bhh1 = (const float*)d_in[8];
  const float* fcw  = (const float*)d_in[9];
  const float* fcb  = (const float*)d_in[10];
  float* out = (float*)d_out;

  // ---- MFMA-path workspace ----
  const size_t pk0B  = (size_t)256 * 48 * 1024 * 2;   // 25,165,824 B
  const size_t pk1B  = (size_t)256 * 64 * 1024 * 2;   // 33,554,432 B
  const size_t slotB = 2 * (size_t)BB * HH * 2;       // 524,288 B (hi+lo)
  const size_t cB    = (size_t)BB * HH * 4;           // 524,288 B
  const size_t needB = pk0B + pk1B + 4 * slotB + 2 * cB;  // 61,865,984 B

  if (needB <= ws_size) {
    char* p = (char*)d_ws;
    unsigned short* pk0  = (unsigned short*)p; p += pk0B;
    unsigned short* pk1  = (unsigned short*)p; p += pk1B;
    unsigned short* h0s0 = (unsigned short*)p; p += slotB;
    unsigned short* h1s0 = (unsigned short*)p; p += slotB;
    char* zblock = p;                         // h0s1, h1s1, c0, c1 (zeroed)
    unsigned short* h0s1 = (unsigned short*)p; p += slotB;
    unsigned short* h1s1 = (unsigned short*)p; p += slotB;
    float* c0 = (float*)p; p += cB;
    float* c1 = (float*)p; p += cB;

    hipMemsetAsync(zblock, 0, 2 * slotB + 2 * cB, stream);

    pack_w2<<<dim3((256 * 48 * 64) / 256), 256, 0, stream>>>(whh0, wih0, pk0, HH, DD);
    pack_w2<<<dim3((256 * 64 * 64) / 256), 256, 0, stream>>>(whh1, wih1, pk1, HH, HH);

    for (int t = 0; t <= TT; ++t) {
      step_dual<<<dim3(256), 512, 0, stream>>>(t, x, pk0, pk1,
                                               h0s0, h0s1, h1s0, h1s1,
                                               bih0, bhh0, bih1, bhh1, c0, c1);
    }

    // final u = 255 (odd) wrote slot[1] = h1s1
    fc_hilo<<<dim3((BB * CO * 64) / 256), 256, 0, stream>>>(h1s1, h1s1 + LOOFF,
                                                            fcw, fcb, out);
    return;
  }

  // ---------------- fallback fp32 path ----------------
  {
    int Tc2 = 64, lt2 = 6;
    while (Tc2 > 1) {
      size_t need = ((size_t)655360 * (size_t)Tc2 + 4u * 131072u + 1024u) * 4u;
      if (need <= ws_size) break;
      Tc2 >>= 1; --lt2;
    }
    float* ws  = (float*)d_ws;
    float* gxc = ws;
    float* hc  = gxc + (size_t)BB * Tc2 * G4H;
    float* c0  = hc + (size_t)BB * Tc2 * HH;
    float* c1  = c0 + (size_t)BB * HH;
    float* h2a = c1 + (size_t)BB * HH;
    float* h2b = h2a + (size_t)BB * HH;
    float* zb  = h2b + (size_t)BB * HH;

    hipMemsetAsync(zb, 0, HH * sizeof(float), stream);
    hipMemsetAsync(c0, 0, (size_t)BB * HH * sizeof(float), stream);
    hipMemsetAsync(c1, 0, (size_t)BB * HH * sizeof(float), stream);

    const dim3 gGemm(G4H / 64, (BB * Tc2) / 64);
    const dim3 gStep(HH / 32, BB / 16);
    const long long gxs = (long long)Tc2 * G4H;
    const long long hcs = (long long)Tc2 * HH;

    const int nChunks = TT / Tc2;
    for (int ci = 0; ci < nChunks; ++ci) {
      const int t0 = ci * Tc2;
      gemm_bias<<<gGemm, 256, 0, stream>>>(x + (size_t)t0 * DD, (long long)TT * DD,
                                           (long long)DD, lt2, wih0, bih0, bhh0,
                                           gxc, G4H, DD);
      for (int tl = 0; tl < Tc2; ++tl) {
        const int t = t0 + tl;
        const float* hprev;
        long long ps;
        if (t == 0) { hprev = zb; ps = 0; }
        else {
          const int ptl = (tl == 0) ? (Tc2 - 1) : (tl - 1);
          hprev = hc + (size_t)ptl * HH; ps = hcs;
        }
        lstm_step<<<gStep, 256, 0, stream>>>(gxc + (size_t)tl * G4H, gxs, whh0,
                                             hprev, ps, hc + (size_t)tl * HH, hcs, c0);
      }
      gemm_bias<<<gGemm, 256, 0, stream>>>(hc, hcs, (long long)HH, lt2,
                                           wih1, bih1, bhh1, gxc, G4H, HH);
      for (int tl = 0; tl < Tc2; ++tl) {
        const int t = t0 + tl;
        const float* hprev;
        long long ps;
        if (t == 0) { hprev = zb; ps = 0; }
        else { hprev = ((t - 1) & 1) ? h2b : h2a; ps = HH; }
        float* hnext = (t & 1) ? h2b : h2a;
        lstm_step<<<gStep, 256, 0, stream>>>(gxc + (size_t)tl * G4H, gxs, whh1,
                                             hprev, ps, hnext, HH, c1);
      }
    }
    fc_kernel<<<dim3((BB * CO * 64) / 256), 256, 0, stream>>>(h2b, fcw, fcb, out);
  }
}

// Round 11
// 8340.410 us; speedup vs baseline: 1.0002x; 1.0002x over previous
//
#include <hip/hip_runtime.h>
#include <math.h>

#define BB 128
#define TT 256
#define DD 512
#define HH 1024
#define G4H 4096
#define CO 7
#define XROW (TT * DD)      // x row stride per batch (fp32 elements)
#define LOOFF (BB * HH)     // offset of lo-plane within an h slot (elements)

typedef __attribute__((ext_vector_type(8))) short bf16x8;
typedef __attribute__((ext_vector_type(4))) float f32x4;

__device__ __forceinline__ unsigned short f2bf(float f) {
  unsigned int u = __float_as_uint(f);
  unsigned int r = (u + 0x7fffu + ((u >> 16) & 1u)) >> 16;
  return (unsigned short)r;
}
__device__ __forceinline__ float bf2f(unsigned short h) {
  return __uint_as_float(((unsigned int)h) << 16);
}
__device__ __forceinline__ float tanh_fast(float x) {
  x = fminf(fmaxf(x, -15.f), 15.f);
  const float e = __expf(2.f * x);
  return (e - 1.f) / (e + 1.f);
}
__device__ __forceinline__ float sigmoid_fast(float x) {
  return 1.f / (1.f + __expf(-x));
}
__device__ __forceinline__ void split8(float4 a, float4 b, bf16x8& hi, bf16x8& lo) {
  float f[8] = {a.x, a.y, a.z, a.w, b.x, b.y, b.z, b.w};
  unsigned short h8[8], l8[8];
#pragma unroll
  for (int e = 0; e < 8; ++e) {
    const unsigned short hh = f2bf(f[e]);
    h8[e] = hh;
    l8[e] = f2bf(f[e] - bf2f(hh));
  }
  hi = *(bf16x8*)h8;
  lo = *(bf16x8*)l8;
}

// ------------------------------------------------------------------
// Pack concatenated weights [Wh | Wx] into fragment-major bf16 hi/lo,
// gate-interleaved n-permutation: srow(n) = (n&3)*1024 + (n>>6)*16 + ((n>>2)&15)
// pk[((nt*KS + ks)*2 + hilo)*512 + l*8 + e] = src[srow(nt*16+(l&15))][ks*32+(l>>4)*8+e]
// ------------------------------------------------------------------
__global__ __launch_bounds__(256)
void pack_w2(const float* __restrict__ Wh, const float* __restrict__ Wx,
             unsigned short* __restrict__ pk, int Kh, int Kx) {
  const int KS = (Kh + Kx) >> 5;
  const int idx = blockIdx.x * 256 + threadIdx.x;
  const int total = 256 * KS * 64;
  if (idx >= total) return;
  const int l = idx & 63;
  const int t2 = idx >> 6;
  const int ks = t2 % KS;
  const int nt = t2 / KS;
  const int n = (nt << 4) + (l & 15);
  const int srow = ((n & 3) << 10) + ((n >> 6) << 4) + ((n >> 2) & 15);
  const int col = (ks << 5) + ((l >> 4) << 3);
  const float* src = (col < Kh) ? (Wh + (size_t)srow * Kh + col)
                                : (Wx + (size_t)srow * Kx + (col - Kh));
  unsigned short hi[8], lo[8];
#pragma unroll
  for (int e = 0; e < 8; ++e) {
    const float v = src[e];
    const unsigned short h = f2bf(v);
    hi[e] = h;
    lo[e] = f2bf(v - bf2f(h));
  }
  const size_t base = (((size_t)nt * KS + ks) * 2) * 512 + (size_t)l * 8;
  *(uint4*)(pk + base) = *(const uint4*)hi;
  *(uint4*)(pk + base + 512) = *(const uint4*)lo;
}

// LDS buffer layout (24576 B per buffer, two buffers):
//  [0, 8192):      W block (2 nt x 64 K): nt*4096 + ksl*2048 + hilo*1024 + l*16
//  [8192, 16384):  A hi bf16: row*128 + ((unit ^ (row&7))<<4)   (64 rows x 64 K)
//  [16384, 24576): A lo bf16 (same addressing)

// ------------------------------------------------------------------
// Diagonal dual-layer step, 2 WGs/CU: 512 WGs x 256 thr. XCD-pairing swizzle:
// bid = xcd | 8*idx; q = (idx&15)<<3 | xcd (32 perm-cols), bh = (idx>>4)&1
// (64-row half), layer = idx>>5. Both bh-halves of a col-group land on the
// same XCD -> second W read is L2-hit. 4 waves = 2 col-tiles x 2 row-halves
// (32 rows each), full K per wave.
// ------------------------------------------------------------------
__global__ __launch_bounds__(256, 2)
void step_dual(int t,
               const float* __restrict__ x,
               const unsigned short* __restrict__ pk0,
               const unsigned short* __restrict__ pk1,
               unsigned short* __restrict__ h0s0, unsigned short* __restrict__ h0s1,
               unsigned short* __restrict__ h1s0, unsigned short* __restrict__ h1s1,
               const float* __restrict__ bih0, const float* __restrict__ bhh0,
               const float* __restrict__ bih1, const float* __restrict__ bhh1,
               float* __restrict__ c0, float* __restrict__ c1) {
  __shared__ __align__(16) char lds0[24576];
  __shared__ __align__(16) char lds1[24576];
  const int bid = blockIdx.x;
  const int xcd = bid & 7;
  const int idx = bid >> 3;
  const int q = ((idx & 15) << 3) | xcd;     // col-group 0..127 (32 perm-cols)
  const int bh = (idx >> 4) & 1;             // 64-row half
  const int layer = (idx >> 5) & 1;
  if (layer == 0 && t >= TT) return;
  if (layer == 1 && t < 1) return;
  const int tid = threadIdx.x;
  const int wid = tid >> 6, l = tid & 63;
  const int ng = wid & 1, rh = wid >> 1;     // col-tile 0..1, row-half 0..1
  const int l15 = l & 15, l4 = l >> 4;

  // per-layer configuration
  const int KS = layer ? 64 : 48;     // K in 32-elem slices
  const int NB = KS >> 1;             // 24 or 32 blocks of 64 K
  const unsigned short* pk = layer ? pk1 : pk0;
  const unsigned short* a1;           // prev-h of own layer (hi base; lo at +LOOFF)
  const unsigned short* a2;           // layer1: h0[t-1]
  unsigned short* ho;
  float* cb;
  const float* bv0;
  const float* bv1;
  if (layer == 0) {
    a1 = (t & 1) ? h0s0 : h0s1;
    ho = (t & 1) ? h0s1 : h0s0;
    a2 = a1;
    cb = c0; bv0 = bih0; bv1 = bhh0;
  } else {
    const int u = t - 1;
    a1 = (u & 1) ? h1s0 : h1s1;
    ho = (u & 1) ? h1s1 : h1s0;
    a2 = (t & 1) ? h0s0 : h0s1;
    cb = c1; bv0 = bih1; bv1 = bhh1;
  }

  // ---- staging maps ----
  // A: thread = (arow 0..63, au 0..3); stages units 2au, 2au+1 (hi+lo)
  const int arow = tid >> 2;
  const int au = tid & 3;
  const int r7w = arow & 7;
  const size_t grow = (size_t)((bh << 6) + arow);
  const unsigned short* a1g = a1 + grow * HH;
  const unsigned short* a2g = a2 + grow * HH;
  const float* xg = x + (size_t)t * DD + grow * XROW;
  const int awh0 = 8192 + arow * 128 + ((((au << 1) + 0) ^ r7w) << 4);
  const int awh1 = 8192 + arow * 128 + ((((au << 1) + 1) ^ r7w) << 4);

  // W: thread = (wksl, whl, wl_); stages both nt at lds t*16 and 4096 + t*16
  const int wksl = (tid >> 7) & 1;
  const int whl = (tid >> 6) & 1;
  const int wl_ = tid & 63;
  const unsigned short* pkgA = pk + (((size_t)(2 * q + 0) * KS + wksl) * 2 + whl) * 512
                                  + (size_t)wl_ * 8;
  const unsigned short* pkgB = pk + (((size_t)(2 * q + 1) * KS + wksl) * 2 + whl) * 512
                                  + (size_t)wl_ * 8;
  // per-block advance = 2048 ushorts

  // ---- read offsets ----
  const int wrb = ng * 4096 + l * 16;        // + ksl*2048 (+1024 for lo)
  const int row0 = (rh << 5) + l15;          // tile0 row; tile1 = +16 (same row&7)
  const int arb0 = 8192 + row0 * 128;
  const int arb1 = arb0 + 16 * 128;
  const int r7r = row0 & 7;

  f32x4 acc0 = (f32x4)(0.f), acc1 = (f32x4)(0.f);
  uint4 qwa, qwb, qa0, qa1, qa2, qa3;

#define LOADW(bb) do {                                        \
    qwa = *(const uint4*)(pkgA + (size_t)(bb) * 2048);        \
    qwb = *(const uint4*)(pkgB + (size_t)(bb) * 2048);        \
  } while (0)

#define LOADA(bb) do {                                                          \
    if ((bb) < 16) {                                                            \
      const unsigned short* s_ = a1g + ((bb) << 6) + (au << 4);                 \
      qa0 = *(const uint4*)s_;           qa1 = *(const uint4*)(s_ + 8);         \
      qa2 = *(const uint4*)(s_ + LOOFF); qa3 = *(const uint4*)(s_ + LOOFF + 8); \
    } else if (layer == 1) {                                                    \
      const unsigned short* s_ = a2g + (((bb) - 16) << 6) + (au << 4);          \
      qa0 = *(const uint4*)s_;           qa1 = *(const uint4*)(s_ + 8);         \
      qa2 = *(const uint4*)(s_ + LOOFF); qa3 = *(const uint4*)(s_ + LOOFF + 8); \
    } else {                                                                    \
      const float* s_ = xg + (((bb) - 16) << 6) + (au << 4);                    \
      qa0 = *(const uint4*)s_;       qa1 = *(const uint4*)(s_ + 4);             \
      qa2 = *(const uint4*)(s_ + 8); qa3 = *(const uint4*)(s_ + 12);            \
    }                                                                           \
  } while (0)

#define WRITEB(buf, bb) do {                                                    \
    *(uint4*)((buf) + tid * 16)        = qwa;                                   \
    *(uint4*)((buf) + 4096 + tid * 16) = qwb;                                   \
    if ((bb) < 16 || layer == 1) {                                              \
      *(uint4*)((buf) + awh0) = qa0; *(uint4*)((buf) + awh1) = qa1;             \
      *(uint4*)((buf) + awh0 + 8192) = qa2; *(uint4*)((buf) + awh1 + 8192) = qa3; \
    } else {                                                                    \
      bf16x8 xh0, xl0, xh1, xl1;                                                \
      split8(*(float4*)&qa0, *(float4*)&qa1, xh0, xl0);                         \
      split8(*(float4*)&qa2, *(float4*)&qa3, xh1, xl1);                         \
      *(bf16x8*)((buf) + awh0) = xh0; *(bf16x8*)((buf) + awh1) = xh1;           \
      *(bf16x8*)((buf) + awh0 + 8192) = xl0; *(bf16x8*)((buf) + awh1 + 8192) = xl1; \
    }                                                                           \
  } while (0)

#define COMPB(buf) do {                                                         \
    _Pragma("unroll")                                                           \
    for (int ksl = 0; ksl < 2; ++ksl) {                                         \
      const bf16x8 wh = *(const bf16x8*)((buf) + wrb + ksl * 2048);             \
      const bf16x8 wl = *(const bf16x8*)((buf) + wrb + ksl * 2048 + 1024);      \
      const int so = ((((ksl << 2) + l4) ^ r7r) << 4);                          \
      const bf16x8 ah0 = *(const bf16x8*)((buf) + arb0 + so);                   \
      const bf16x8 al0 = *(const bf16x8*)((buf) + arb0 + so + 8192);            \
      const bf16x8 ah1 = *(const bf16x8*)((buf) + arb1 + so);                   \
      const bf16x8 al1 = *(const bf16x8*)((buf) + arb1 + so + 8192);            \
      acc0 = __builtin_amdgcn_mfma_f32_16x16x32_bf16(ah0, wh, acc0, 0, 0, 0);   \
      acc0 = __builtin_amdgcn_mfma_f32_16x16x32_bf16(ah0, wl, acc0, 0, 0, 0);   \
      acc0 = __builtin_amdgcn_mfma_f32_16x16x32_bf16(al0, wh, acc0, 0, 0, 0);   \
      acc1 = __builtin_amdgcn_mfma_f32_16x16x32_bf16(ah1, wh, acc1, 0, 0, 0);   \
      acc1 = __builtin_amdgcn_mfma_f32_16x16x32_bf16(ah1, wl, acc1, 0, 0, 0);   \
      acc1 = __builtin_amdgcn_mfma_f32_16x16x32_bf16(al1, wh, acc1, 0, 0, 0);   \
    }                                                                           \
  } while (0)

  // prologue: stage block 0
  LOADW(0); LOADA(0);
  WRITEB(lds0, 0);
  __syncthreads();

  for (int b = 0; b < NB; ++b) {
    char* cur = (b & 1) ? lds1 : lds0;
    char* nxt = (b & 1) ? lds0 : lds1;
    if (b + 1 < NB) { LOADW(b + 1); LOADA(b + 1); }
    COMPB(cur);
    if (b + 1 < NB) WRITEB(nxt, b + 1);
    __syncthreads();
  }
#undef LOADW
#undef LOADA
#undef WRITEB
#undef COMPB

  // epilogue: bias + cell + h store (quad shfl gather over l15&3)
  const int n = ((q << 1) + ng) * 16 + l15;
  const int srn = ((n & 3) << 10) + ((n >> 6) << 4) + ((n >> 2) & 15);
  const float bn = bv0[srn] + bv1[srn];
  const int g = l15 & 3;
  const int j = srn & 1023;
  f32x4 accs[2] = {acc0, acc1};
#pragma unroll
  for (int mt = 0; mt < 2; ++mt) {
#pragma unroll
    for (int r = 0; r < 4; ++r) {
      const float v = accs[mt][r] + bn;
      const float v1 = __shfl_xor(v, 1);
      const float v2 = __shfl_xor(v, 2);
      const float v3 = __shfl_xor(v, 3);
      if (g == 0) {
        const int row = (bh << 6) + (rh << 5) + (mt << 4) + (l4 << 2) + r;
        const float si = sigmoid_fast(v);
        const float sf = sigmoid_fast(v1);
        const float tg = tanh_fast(v2);
        const float so = sigmoid_fast(v3);
        const size_t ci = (size_t)row * HH + j;
        const float cn = sf * cb[ci] + si * tg;
        cb[ci] = cn;
        const float h = so * tanh_fast(cn);
        const unsigned short hh = f2bf(h);
        ho[(size_t)row * HH + j] = hh;
        ho[LOOFF + (size_t)row * HH + j] = f2bf(h - bf2f(hh));
      }
    }
  }
}

// ------------------------------------------------------------------
// FC from hi/lo h slot
// ------------------------------------------------------------------
__global__ __launch_bounds__(256)
void fc_hilo(const unsigned short* __restrict__ hhi, const unsigned short* __restrict__ hlo,
             const float* __restrict__ fcw, const float* __restrict__ fcb,
             float* __restrict__ out) {
  const int gw = (int)((blockIdx.x * 256 + threadIdx.x) >> 6);
  const int lane = threadIdx.x & 63;
  const int b = gw / CO;
  const int n = gw - b * CO;
  const unsigned short* hp = hhi + (size_t)b * HH;
  const unsigned short* lp = hlo + (size_t)b * HH;
  const float* wp = fcw + (size_t)n * HH;
  float s = 0.f;
  for (int k = lane; k < HH; k += 64) s += (bf2f(hp[k]) + bf2f(lp[k])) * wp[k];
#pragma unroll
  for (int off = 32; off; off >>= 1) s += __shfl_down(s, off);
  if (lane == 0) out[b * CO + n] = s + fcb[n];
}

// ==================================================================
// Fallback fp32 path (round-2 kernels, used only if ws_size is small)
// ==================================================================
__global__ __launch_bounds__(256)
void gemm_bias(const float* __restrict__ A, long long sOut, long long sIn, int lt,
               const float* __restrict__ W,
               const float* __restrict__ b0, const float* __restrict__ b1,
               float* __restrict__ C, int N, int K) {
  __shared__ float as[16][64];
  __shared__ float wsh[16][64];
  const int tid = threadIdx.x;
  const int bm = blockIdx.y << 6;
  const int bn = blockIdx.x << 6;
  const int tr = (tid >> 4) << 2;
  const int tc = (tid & 15) << 2;
  const int lrow = tid >> 2;
  const int lk4 = (tid & 3) << 2;
  const int msk = (1 << lt) - 1;
  const int r = bm + lrow;
  const float* ap = A + (size_t)(r >> lt) * sOut + (size_t)(r & msk) * sIn + lk4;
  const float* wp = W + (size_t)(bn + lrow) * K + lk4;
  float acc[4][4] = {};
  for (int k0 = 0; k0 < K; k0 += 16) {
    const float4 av = *(const float4*)(ap + k0);
    const float4 wv = *(const float4*)(wp + k0);
    __syncthreads();
    as[lk4 + 0][lrow] = av.x; as[lk4 + 1][lrow] = av.y;
    as[lk4 + 2][lrow] = av.z; as[lk4 + 3][lrow] = av.w;
    wsh[lk4 + 0][lrow] = wv.x; wsh[lk4 + 1][lrow] = wv.y;
    wsh[lk4 + 2][lrow] = wv.z; wsh[lk4 + 3][lrow] = wv.w;
    __syncthreads();
#pragma unroll
    for (int k = 0; k < 16; ++k) {
      const float4 a = *(const float4*)&as[k][tr];
      const float4 b = *(const float4*)&wsh[k][tc];
      acc[0][0] += a.x * b.x; acc[0][1] += a.x * b.y; acc[0][2] += a.x * b.z; acc[0][3] += a.x * b.w;
      acc[1][0] += a.y * b.x; acc[1][1] += a.y * b.y; acc[1][2] += a.y * b.z; acc[1][3] += a.y * b.w;
      acc[2][0] += a.z * b.x; acc[2][1] += a.z * b.y; acc[2][2] += a.z * b.z; acc[2][3] += a.z * b.w;
      acc[3][0] += a.w * b.x; acc[3][1] += a.w * b.y; acc[3][2] += a.w * b.z; acc[3][3] += a.w * b.w;
    }
  }
  const float* bp0 = b0 + bn + tc;
  const float* bp1 = b1 + bn + tc;
#pragma unroll
  for (int i = 0; i < 4; ++i) {
    float* cp = C + (size_t)(bm + tr + i) * N + bn + tc;
#pragma unroll
    for (int j = 0; j < 4; ++j) cp[j] = acc[i][j] + bp0[j] + bp1[j];
  }
}

__global__ __launch_bounds__(256)
void lstm_step(const float* __restrict__ gx, long long gxstride,
               const float* __restrict__ whh,
               const float* __restrict__ hprev, long long pstride,
               float* __restrict__ hnext, long long nstride,
               float* __restrict__ cbuf) {
  __shared__ float hs[32][16];
  __shared__ float wsm[32][4][32];
  const int tid = threadIdx.x;
  const int jt = blockIdx.x << 5;
  const int bm = blockIdx.y << 4;
  const int col = tid & 31;
  const int rp = (tid >> 5) << 1;
  const int hr = tid >> 4;
  const int hk = (tid & 15) << 1;
  const int wrow = tid & 127;
  const int wg = wrow >> 5;
  const int wc = wrow & 31;
  const int wk = (tid >> 7) << 4;
  const float* wbase = whh + (size_t)(wg * HH + jt + wc) * HH + wk;
  const float* hbase = hprev + (size_t)(bm + hr) * pstride + hk;

  float acc[4][2] = {};
  for (int k0 = 0; k0 < HH; k0 += 32) {
    const float2 hv = *(const float2*)(hbase + k0);
    const float4 wv0 = *(const float4*)(wbase + k0);
    const float4 wv1 = *(const float4*)(wbase + k0 + 4);
    const float4 wv2 = *(const float4*)(wbase + k0 + 8);
    const float4 wv3 = *(const float4*)(wbase + k0 + 12);
    __syncthreads();
    hs[hk][hr] = hv.x; hs[hk + 1][hr] = hv.y;
    {
      const float wvv[16] = {wv0.x, wv0.y, wv0.z, wv0.w, wv1.x, wv1.y, wv1.z, wv1.w,
                             wv2.x, wv2.y, wv2.z, wv2.w, wv3.x, wv3.y, wv3.z, wv3.w};
#pragma unroll
      for (int i = 0; i < 16; ++i) wsm[wk + i][wg][wc] = wvv[i];
    }
    __syncthreads();
#pragma unroll
    for (int k = 0; k < 32; ++k) {
      const float2 a = *(const float2*)&hs[k][rp];
      const float wi = wsm[k][0][col];
      const float wf = wsm[k][1][col];
      const float wg_ = wsm[k][2][col];
      const float wo = wsm[k][3][col];
      acc[0][0] += a.x * wi;  acc[0][1] += a.y * wi;
      acc[1][0] += a.x * wf;  acc[1][1] += a.y * wf;
      acc[2][0] += a.x * wg_; acc[2][1] += a.y * wg_;
      acc[3][0] += a.x * wo;  acc[3][1] += a.y * wo;
    }
  }
#pragma unroll
  for (int rr = 0; rr < 2; ++rr) {
    const int b = bm + rp + rr;
    const int j = jt + col;
    const size_t gxo = (size_t)b * gxstride + j;
    const float gi = acc[0][rr] + gx[gxo];
    const float gf = acc[1][rr] + gx[gxo + HH];
    const float gg = acc[2][rr] + gx[gxo + 2 * HH];
    const float go = acc[3][rr] + gx[gxo + 3 * HH];
    const float si = 1.f / (1.f + expf(-gi));
    const float sf = 1.f / (1.f + expf(-gf));
    const float so = 1.f / (1.f + expf(-go));
    const size_t cidx = (size_t)b * HH + j;
    const float cn = sf * cbuf[cidx] + si * tanhf(gg);
    cbuf[cidx] = cn;
    hnext[(size_t)b * nstride + j] = so * tanhf(cn);
  }
}

__global__ __launch_bounds__(256)
void fc_kernel(const float* __restrict__ hlast, const float* __restrict__ fcw,
               const float* __restrict__ fcb, float* __restrict__ out) {
  const int gw = (int)((blockIdx.x * 256 + threadIdx.x) >> 6);
  const int lane = threadIdx.x & 63;
  const int b = gw / CO;
  const int n = gw - b * CO;
  const float* hp = hlast + (size_t)b * HH;
  const float* wp = fcw + (size_t)n * HH;
  float s = 0.f;
  for (int k = lane; k < HH; k += 64) s += hp[k] * wp[k];
#pragma unroll
  for (int off = 32; off; off >>= 1) s += __shfl_down(s, off);
  if (lane == 0) out[b * CO + n] = s + fcb[n];
}

// ==================================================================
extern "C" void kernel_launch(void* const* d_in, const int* in_sizes, int n_in,
                              void* d_out, int out_size, void* d_ws, size_t ws_size,
                              hipStream_t stream) {
  const float* x    = (const float*)d_in[0];
  const float* wih0 = (const float*)d_in[1];
  const float* whh0 = (const float*)d_in[2];
  const float* bih0 = (const float*)d_in[3];
  const float* bhh0 = (const float*)d_in[4];
  const float* wih1 = (const float*)d_in[5];
  const float* whh1 = (const float*)d_in[6];
  const float* bih1 = (const float*)d_in[7];
  const float* bhh1 = (const float*)d_in[8];
  const float* fcw  = (const float*)d_in[9];
  const float* fcb  = (const float*)d_in[10];
  float* out = (float*)d_out;

  // ---- MFMA-path workspace ----
  const size_t pk0B  = (size_t)256 * 48 * 1024 * 2;   // 25,165,824 B
  const size_t pk1B  = (size_t)256 * 64 * 1024 * 2;   // 33,554,432 B
  const size_t slotB = 2 * (size_t)BB * HH * 2;       // 524,288 B (hi+lo)
  const size_t cB    = (size_t)BB * HH * 4;           // 524,288 B
  const size_t needB = pk0B + pk1B + 4 * slotB + 2 * cB;  // 61,865,984 B

  if (needB <= ws_size) {
    char* p = (char*)d_ws;
    unsigned short* pk0  = (unsigned short*)p; p += pk0B;
    unsigned short* pk1  = (unsigned short*)p; p += pk1B;
    unsigned short* h0s0 = (unsigned short*)p; p += slotB;
    unsigned short* h1s0 = (unsigned short*)p; p += slotB;
    char* zblock = p;                         // h0s1, h1s1, c0, c1 (zeroed)
    unsigned short* h0s1 = (unsigned short*)p; p += slotB;
    unsigned short* h1s1 = (unsigned short*)p; p += slotB;
    float* c0 = (float*)p; p += cB;
    float* c1 = (float*)p; p += cB;

    hipMemsetAsync(zblock, 0, 2 * slotB + 2 * cB, stream);

    pack_w2<<<dim3((256 * 48 * 64) / 256), 256, 0, stream>>>(whh0, wih0, pk0, HH, DD);
    pack_w2<<<dim3((256 * 64 * 64) / 256), 256, 0, stream>>>(whh1, wih1, pk1, HH, HH);

    for (int t = 0; t <= TT; ++t) {
      step_dual<<<dim3(512), 256, 0, stream>>>(t, x, pk0, pk1,
                                               h0s0, h0s1, h1s0, h1s1,
                                               bih0, bhh0, bih1, bhh1, c0, c1);
    }

    // final u = 255 (odd) wrote slot[1] = h1s1
    fc_hilo<<<dim3((BB * CO * 64) / 256), 256, 0, stream>>>(h1s1, h1s1 + LOOFF,
                                                            fcw, fcb, out);
    return;
  }

  // ---------------- fallback fp32 path ----------------
  {
    int Tc2 = 64, lt2 = 6;
    while (Tc2 > 1) {
      size_t need = ((size_t)655360 * (size_t)Tc2 + 4u * 131072u + 1024u) * 4u;
      if (need <= ws_size) break;
      Tc2 >>= 1; --lt2;
    }
    float* ws  = (float*)d_ws;
    float* gxc = ws;
    float* hc  = gxc + (size_t)BB * Tc2 * G4H;
    float* c0  = hc + (size_t)BB * Tc2 * HH;
    float* c1  = c0 + (size_t)BB * HH;
    float* h2a = c1 + (size_t)BB * HH;
    float* h2b = h2a + (size_t)BB * HH;
    float* zb  = h2b + (size_t)BB * HH;

    hipMemsetAsync(zb, 0, HH * sizeof(float), stream);
    hipMemsetAsync(c0, 0, (size_t)BB * HH * sizeof(float), stream);
    hipMemsetAsync(c1, 0, (size_t)BB * HH * sizeof(float), stream);

    const dim3 gGemm(G4H / 64, (BB * Tc2) / 64);
    const dim3 gStep(HH / 32, BB / 16);
    const long long gxs = (long long)Tc2 * G4H;
    const long long hcs = (long long)Tc2 * HH;

    const int nChunks = TT / Tc2;
    for (int ci = 0; ci < nChunks; ++ci) {
      const int t0 = ci * Tc2;
      gemm_bias<<<gGemm, 256, 0, stream>>>(x + (size_t)t0 * DD, (long long)TT * DD,
                                           (long long)DD, lt2, wih0, bih0, bhh0,
                                           gxc, G4H, DD);
      for (int tl = 0; tl < Tc2; ++tl) {
        const int t = t0 + tl;
        const float* hprev;
        long long ps;
        if (t == 0) { hprev = zb; ps = 0; }
        else {
          const int ptl = (tl == 0) ? (Tc2 - 1) : (tl - 1);
          hprev = hc + (size_t)ptl * HH; ps = hcs;
        }
        lstm_step<<<gStep, 256, 0, stream>>>(gxc + (size_t)tl * G4H, gxs, whh0,
                                             hprev, ps, hc + (size_t)tl * HH, hcs, c0);
      }
      gemm_bias<<<gGemm, 256, 0, stream>>>(hc, hcs, (long long)HH, lt2,
                                           wih1, bih1, bhh1, gxc, G4H, HH);
      for (int tl = 0; tl < Tc2; ++tl) {
        const int t = t0 + tl;
        const float* hprev;
        long long ps;
        if (t == 0) { hprev = zb; ps = 0; }
        else { hprev = ((t - 1) & 1) ? h2b : h2a; ps = HH; }
        float* hnext = (t & 1) ? h2b : h2a;
        lstm_step<<<gStep, 256, 0, stream>>>(gxc + (size_t)tl * G4H, gxs, whh1,
                                             hprev, ps, hnext, HH, c1);
      }
    }
    fc_kernel<<<dim3((BB * CO * 64) / 256), 256, 0, stream>>>(h2b, fcw, fcb, out);
  }
}

// Round 12
// 7925.592 us; speedup vs baseline: 1.0525x; 1.0523x over previous
//
#include <hip/hip_runtime.h>
#include <math.h>

#define BB 128
#define TT 256
#define DD 512
#define HH 1024
#define G4H 4096
#define CO 7
#define XROW (TT * DD)      // x row stride per batch (fp32 elements)
#define LOOFF (BB * HH)     // offset of lo-plane within an h slot (elements)

typedef __attribute__((ext_vector_type(8))) short bf16x8;
typedef __attribute__((ext_vector_type(4))) float f32x4;

__device__ __forceinline__ unsigned short f2bf(float f) {
  unsigned int u = __float_as_uint(f);
  unsigned int r = (u + 0x7fffu + ((u >> 16) & 1u)) >> 16;
  return (unsigned short)r;
}
__device__ __forceinline__ float bf2f(unsigned short h) {
  return __uint_as_float(((unsigned int)h) << 16);
}
__device__ __forceinline__ float tanh_fast(float x) {
  x = fminf(fmaxf(x, -15.f), 15.f);
  const float e = __expf(2.f * x);
  return (e - 1.f) / (e + 1.f);
}
__device__ __forceinline__ float sigmoid_fast(float x) {
  return 1.f / (1.f + __expf(-x));
}
__device__ __forceinline__ void split8(float4 a, float4 b, bf16x8& hi, bf16x8& lo) {
  float f[8] = {a.x, a.y, a.z, a.w, b.x, b.y, b.z, b.w};
  unsigned short h8[8], l8[8];
#pragma unroll
  for (int e = 0; e < 8; ++e) {
    const unsigned short hh = f2bf(f[e]);
    h8[e] = hh;
    l8[e] = f2bf(f[e] - bf2f(hh));
  }
  hi = *(bf16x8*)h8;
  lo = *(bf16x8*)l8;
}

// ------------------------------------------------------------------
// Pack concatenated weights [Wh | Wx] into fragment-major bf16 hi/lo,
// gate-interleaved n-permutation: srow(n) = (n&3)*1024 + (n>>6)*16 + ((n>>2)&15)
// pk[((nt*KS + ks)*2 + hilo)*512 + l*8 + e] = src[srow(nt*16+(l&15))][ks*32+(l>>4)*8+e]
// ------------------------------------------------------------------
__global__ __launch_bounds__(256)
void pack_w2(const float* __restrict__ Wh, const float* __restrict__ Wx,
             unsigned short* __restrict__ pk, int Kh, int Kx) {
  const int KS = (Kh + Kx) >> 5;
  const int idx = blockIdx.x * 256 + threadIdx.x;
  const int total = 256 * KS * 64;
  if (idx >= total) return;
  const int l = idx & 63;
  const int t2 = idx >> 6;
  const int ks = t2 % KS;
  const int nt = t2 / KS;
  const int n = (nt << 4) + (l & 15);
  const int srow = ((n & 3) << 10) + ((n >> 6) << 4) + ((n >> 2) & 15);
  const int col = (ks << 5) + ((l >> 4) << 3);
  const float* src = (col < Kh) ? (Wh + (size_t)srow * Kh + col)
                                : (Wx + (size_t)srow * Kx + (col - Kh));
  unsigned short hi[8], lo[8];
#pragma unroll
  for (int e = 0; e < 8; ++e) {
    const float v = src[e];
    const unsigned short h = f2bf(v);
    hi[e] = h;
    lo[e] = f2bf(v - bf2f(h));
  }
  const size_t base = (((size_t)nt * KS + ks) * 2) * 512 + (size_t)l * 8;
  *(uint4*)(pk + base) = *(const uint4*)hi;
  *(uint4*)(pk + base + 512) = *(const uint4*)lo;
}

// LDS buffer layout (64 KB per buffer, two buffers):
//  [0, 32768):      W block: nt*8192 + ksl*2048 + hilo*1024 + l*16
//  [32768, 49152):  A hi bf16: row*256 + ((unit16 ^ (row&15))<<4)   (64 rows x 128 k)
//  [49152, 65536):  A lo bf16 (x-blocks only; h is single-plane)

// h-blocks: A single bf16 -> 4 MFMA per ksl (A*Whi + A*Wlo, both row-tiles)
__device__ __forceinline__ void comp_h(const char* buf, int ngoff, int arb, int l4, int l15,
                                       f32x4& acc0, f32x4& acc1) {
#pragma unroll
  for (int ksl = 0; ksl < 4; ++ksl) {
    const bf16x8 wh = *(const bf16x8*)(buf + ngoff + ksl * 2048);
    const bf16x8 wl = *(const bf16x8*)(buf + ngoff + ksl * 2048 + 1024);
    const int so = (((ksl << 2) + l4) ^ l15) << 4;
    const bf16x8 ah0 = *(const bf16x8*)(buf + arb + so);
    const bf16x8 ah1 = *(const bf16x8*)(buf + arb + so + 4096);
    acc0 = __builtin_amdgcn_mfma_f32_16x16x32_bf16(ah0, wh, acc0, 0, 0, 0);
    acc0 = __builtin_amdgcn_mfma_f32_16x16x32_bf16(ah0, wl, acc0, 0, 0, 0);
    acc1 = __builtin_amdgcn_mfma_f32_16x16x32_bf16(ah1, wh, acc1, 0, 0, 0);
    acc1 = __builtin_amdgcn_mfma_f32_16x16x32_bf16(ah1, wl, acc1, 0, 0, 0);
  }
}

// x-blocks: A hi/lo -> 6 MFMA per ksl (R6 path, unchanged)
__device__ __forceinline__ void comp_x6(const char* buf, int ngoff, int arb, int l4, int l15,
                                        f32x4& acc0, f32x4& acc1) {
#pragma unroll
  for (int ksl = 0; ksl < 4; ++ksl) {
    const bf16x8 wh = *(const bf16x8*)(buf + ngoff + ksl * 2048);
    const bf16x8 wl = *(const bf16x8*)(buf + ngoff + ksl * 2048 + 1024);
    const int so = (((ksl << 2) + l4) ^ l15) << 4;
    const bf16x8 ah0 = *(const bf16x8*)(buf + arb + so);
    const bf16x8 al0 = *(const bf16x8*)(buf + arb + so + 16384);
    const bf16x8 ah1 = *(const bf16x8*)(buf + arb + so + 4096);
    const bf16x8 al1 = *(const bf16x8*)(buf + arb + so + 4096 + 16384);
    acc0 = __builtin_amdgcn_mfma_f32_16x16x32_bf16(ah0, wh, acc0, 0, 0, 0);
    acc0 = __builtin_amdgcn_mfma_f32_16x16x32_bf16(ah0, wl, acc0, 0, 0, 0);
    acc0 = __builtin_amdgcn_mfma_f32_16x16x32_bf16(al0, wh, acc0, 0, 0, 0);
    acc1 = __builtin_amdgcn_mfma_f32_16x16x32_bf16(ah1, wh, acc1, 0, 0, 0);
    acc1 = __builtin_amdgcn_mfma_f32_16x16x32_bf16(ah1, wl, acc1, 0, 0, 0);
    acc1 = __builtin_amdgcn_mfma_f32_16x16x32_bf16(al1, wh, acc1, 0, 0, 0);
  }
}

// ------------------------------------------------------------------
// Diagonal dual-layer step (R6 structure): WGs 0..127 run layer0 @ t,
// WGs 128..255 run layer1 @ t-1. 512 thr/WG, 64KB x2 LDS double buffer,
// 1-deep prefetch, plain __syncthreads. h operand = SINGLE bf16 plane;
// x operand = hi/lo (converted at staging); W = hi/lo.
// ------------------------------------------------------------------
__global__ __launch_bounds__(512, 1)
void step_dual(int t,
               const float* __restrict__ x,
               const unsigned short* __restrict__ pk0,
               const unsigned short* __restrict__ pk1,
               unsigned short* __restrict__ h0s0, unsigned short* __restrict__ h0s1,
               unsigned short* __restrict__ h1s0, unsigned short* __restrict__ h1s1,
               const float* __restrict__ bih0, const float* __restrict__ bhh0,
               const float* __restrict__ bih1, const float* __restrict__ bhh1,
               float* __restrict__ c0, float* __restrict__ c1) {
  __shared__ __align__(16) char lds0[65536];
  __shared__ __align__(16) char lds1[65536];
  const int bid = blockIdx.x;
  const int layer = bid >> 7;
  if (layer == 0 && t >= TT) return;
  if (layer == 1 && t < 1) return;
  const int lbid = bid & 127;
  const int jg = lbid & 63, bh = lbid >> 6;
  const int tid = threadIdx.x;
  const int wid = tid >> 6, l = tid & 63;
  const int mh = wid & 1, ng = wid >> 1;
  const int l15 = l & 15, l4 = l >> 4;
  const int nl = (ng << 4) + l15;

  // per-layer configuration
  const int KS = layer ? 64 : 48;
  const int NB = KS >> 2;            // 12 or 16 blocks of 4 k-slices
  const unsigned short* pk = layer ? pk1 : pk0;
  const unsigned short* a1;          // prev-h of own layer (hi plane used)
  const unsigned short* a2;          // layer1: h0[t-1]
  unsigned short* ho;
  float* cb;
  const float* bv0;
  const float* bv1;
  if (layer == 0) {
    a1 = (t & 1) ? h0s0 : h0s1;
    ho = (t & 1) ? h0s1 : h0s0;
    a2 = a1;
    cb = c0; bv0 = bih0; bv1 = bhh0;
  } else {
    const int u = t - 1;
    a1 = (u & 1) ? h1s0 : h1s1;
    ho = (u & 1) ? h1s1 : h1s0;
    a2 = (t & 1) ? h0s0 : h0s1;
    cb = c1; bv0 = bih1; bv1 = bhh1;
  }

  // staging maps: thread = (arow 0..63, aseg 0..7); units aseg & aseg+8
  const int arow = tid >> 3;
  const int aseg = tid & 7;
  const int swA = arow & 15;
  const size_t growA = (size_t)((bh << 6) + arow);
  const unsigned short* a1g = a1 + growA * HH;
  const unsigned short* a2g = a2 + growA * HH;
  const float* xg = x + (size_t)t * DD + growA * XROW;

  const unsigned short* pkc0 = pk + ((size_t)(jg * 4 + 0) * KS) * 1024 + (size_t)tid * 8;
  const unsigned short* pkc1 = pk + ((size_t)(jg * 4 + 1) * KS) * 1024 + (size_t)tid * 8;
  const unsigned short* pkc2 = pk + ((size_t)(jg * 4 + 2) * KS) * 1024 + (size_t)tid * 8;
  const unsigned short* pkc3 = pk + ((size_t)(jg * 4 + 3) * KS) * 1024 + (size_t)tid * 8;

  // LDS write offsets (hi plane; lo plane at +16384, x-blocks only)
  const int aw0 = 32768 + arow * 256 + ((aseg ^ swA) << 4);
  const int aw1 = 32768 + arow * 256 + (((aseg + 8) ^ swA) << 4);

  // LDS read offsets
  const int ngoff = ng * 8192 + l * 16;
  const int arb = 32768 + (mh * 32 + l15) * 256;

  f32x4 acc0 = (f32x4)(0.f), acc1 = (f32x4)(0.f);
  uint4 qw0, qw1, qw2, qw3, qa0, qa1, qa2, qa3;

#define LOADW(bb) do {                                        \
    qw0 = *(const uint4*)(pkc0 + (size_t)(bb) * 4096);        \
    qw1 = *(const uint4*)(pkc1 + (size_t)(bb) * 4096);        \
    qw2 = *(const uint4*)(pkc2 + (size_t)(bb) * 4096);        \
    qw3 = *(const uint4*)(pkc3 + (size_t)(bb) * 4096);        \
  } while (0)

  // h blocks: qa0/qa1 = hi units aseg, aseg+8 (single plane).
  // x blocks: qa0..qa3 = raw fp32 (converted to hi/lo at write time).
#define LOADA(bb) do {                                                          \
    if ((bb) < 8) {                                                             \
      const unsigned short* s_ = a1g + ((bb) << 7) + (size_t)aseg * 8;          \
      qa0 = *(const uint4*)s_;           qa1 = *(const uint4*)(s_ + 64);        \
    } else if (layer == 1) {                                                    \
      const unsigned short* s_ = a2g + (((bb) - 8) << 7) + (size_t)aseg * 8;    \
      qa0 = *(const uint4*)s_;           qa1 = *(const uint4*)(s_ + 64);        \
    } else {                                                                    \
      const float* s_ = xg + (((bb) - 8) << 7) + (size_t)aseg * 8;              \
      qa0 = *(const uint4*)s_;        qa1 = *(const uint4*)(s_ + 4);            \
      qa2 = *(const uint4*)(s_ + 64); qa3 = *(const uint4*)(s_ + 68);           \
    }                                                                           \
  } while (0)

#define WRITEB(buf, bb) do {                                                    \
    *(uint4*)((buf) + tid * 16)         = qw0;                                  \
    *(uint4*)((buf) + 8192 + tid * 16)  = qw1;                                  \
    *(uint4*)((buf) + 16384 + tid * 16) = qw2;                                  \
    *(uint4*)((buf) + 24576 + tid * 16) = qw3;                                  \
    if ((bb) < 8 || layer == 1) {                                               \
      *(uint4*)((buf) + aw0) = qa0; *(uint4*)((buf) + aw1) = qa1;               \
    } else {                                                                    \
      bf16x8 xh0, xl0, xh1, xl1;                                                \
      split8(*(float4*)&qa0, *(float4*)&qa1, xh0, xl0);                         \
      split8(*(float4*)&qa2, *(float4*)&qa3, xh1, xl1);                         \
      *(bf16x8*)((buf) + aw0) = xh0; *(bf16x8*)((buf) + aw1) = xh1;             \
      *(bf16x8*)((buf) + aw0 + 16384) = xl0; *(bf16x8*)((buf) + aw1 + 16384) = xl1; \
    }                                                                           \
  } while (0)

  // prologue: stage block 0
  LOADW(0); LOADA(0);
  WRITEB(lds0, 0);
  __syncthreads();

  for (int b = 0; b < NB; ++b) {
    char* cur = (b & 1) ? lds1 : lds0;
    char* nxt = (b & 1) ? lds0 : lds1;
    if (b + 1 < NB) { LOADW(b + 1); LOADA(b + 1); }
    if (b < 8 || layer == 1) comp_h(cur, ngoff, arb, l4, l15, acc0, acc1);
    else                     comp_x6(cur, ngoff, arb, l4, l15, acc0, acc1);
    if (b + 1 < NB) WRITEB(nxt, b + 1);
    __syncthreads();
  }
#undef LOADW
#undef LOADA
#undef WRITEB

  // epilogue: bias + cell + h store (quad shfl gather: g = nl&3)
  // (lo plane still stored: final FC uses hi+lo)
  const int n = (jg << 6) + nl;
  const int srow = ((n & 3) << 10) + ((n >> 6) << 4) + ((n >> 2) & 15);
  const float bn = bv0[srow] + bv1[srow];
  const int g = nl & 3;
  const int j = (jg << 4) + (nl >> 2);
  f32x4 accs[2] = {acc0, acc1};
#pragma unroll
  for (int mt = 0; mt < 2; ++mt) {
#pragma unroll
    for (int r = 0; r < 4; ++r) {
      const float v = accs[mt][r] + bn;
      const float v1 = __shfl_xor(v, 1);
      const float v2 = __shfl_xor(v, 2);
      const float v3 = __shfl_xor(v, 3);
      if (g == 0) {
        const int b = (bh << 6) + (mh << 5) + (mt << 4) + (l4 << 2) + r;
        const float si = sigmoid_fast(v);
        const float sf = sigmoid_fast(v1);
        const float tg = tanh_fast(v2);
        const float so = sigmoid_fast(v3);
        const size_t ci = (size_t)b * HH + j;
        const float cn = sf * cb[ci] + si * tg;
        cb[ci] = cn;
        const float h = so * tanh_fast(cn);
        const unsigned short hh = f2bf(h);
        ho[(size_t)b * HH + j] = hh;
        ho[LOOFF + (size_t)b * HH + j] = f2bf(h - bf2f(hh));
      }
    }
  }
}

// ------------------------------------------------------------------
// FC from hi/lo h slot
// ------------------------------------------------------------------
__global__ __launch_bounds__(256)
void fc_hilo(const unsigned short* __restrict__ hhi, const unsigned short* __restrict__ hlo,
             const float* __restrict__ fcw, const float* __restrict__ fcb,
             float* __restrict__ out) {
  const int gw = (int)((blockIdx.x * 256 + threadIdx.x) >> 6);
  const int lane = threadIdx.x & 63;
  const int b = gw / CO;
  const int n = gw - b * CO;
  const unsigned short* hp = hhi + (size_t)b * HH;
  const unsigned short* lp = hlo + (size_t)b * HH;
  const float* wp = fcw + (size_t)n * HH;
  float s = 0.f;
  for (int k = lane; k < HH; k += 64) s += (bf2f(hp[k]) + bf2f(lp[k])) * wp[k];
#pragma unroll
  for (int off = 32; off; off >>= 1) s += __shfl_down(s, off);
  if (lane == 0) out[b * CO + n] = s + fcb[n];
}

// ==================================================================
// Fallback fp32 path (round-2 kernels, used only if ws_size is small)
// ==================================================================
__global__ __launch_bounds__(256)
void gemm_bias(const float* __restrict__ A, long long sOut, long long sIn, int lt,
               const float* __restrict__ W,
               const float* __restrict__ b0, const float* __restrict__ b1,
               float* __restrict__ C, int N, int K) {
  __shared__ float as[16][64];
  __shared__ float wsh[16][64];
  const int tid = threadIdx.x;
  const int bm = blockIdx.y << 6;
  const int bn = blockIdx.x << 6;
  const int tr = (tid >> 4) << 2;
  const int tc = (tid & 15) << 2;
  const int lrow = tid >> 2;
  const int lk4 = (tid & 3) << 2;
  const int msk = (1 << lt) - 1;
  const int r = bm + lrow;
  const float* ap = A + (size_t)(r >> lt) * sOut + (size_t)(r & msk) * sIn + lk4;
  const float* wp = W + (size_t)(bn + lrow) * K + lk4;
  float acc[4][4] = {};
  for (int k0 = 0; k0 < K; k0 += 16) {
    const float4 av = *(const float4*)(ap + k0);
    const float4 wv = *(const float4*)(wp + k0);
    __syncthreads();
    as[lk4 + 0][lrow] = av.x; as[lk4 + 1][lrow] = av.y;
    as[lk4 + 2][lrow] = av.z; as[lk4 + 3][lrow] = av.w;
    wsh[lk4 + 0][lrow] = wv.x; wsh[lk4 + 1][lrow] = wv.y;
    wsh[lk4 + 2][lrow] = wv.z; wsh[lk4 + 3][lrow] = wv.w;
    __syncthreads();
#pragma unroll
    for (int k = 0; k < 16; ++k) {
      const float4 a = *(const float4*)&as[k][tr];
      const float4 b = *(const float4*)&wsh[k][tc];
      acc[0][0] += a.x * b.x; acc[0][1] += a.x * b.y; acc[0][2] += a.x * b.z; acc[0][3] += a.x * b.w;
      acc[1][0] += a.y * b.x; acc[1][1] += a.y * b.y; acc[1][2] += a.y * b.z; acc[1][3] += a.y * b.w;
      acc[2][0] += a.z * b.x; acc[2][1] += a.z * b.y; acc[2][2] += a.z * b.z; acc[2][3] += a.z * b.w;
      acc[3][0] += a.w * b.x; acc[3][1] += a.w * b.y; acc[3][2] += a.w * b.z; acc[3][3] += a.w * b.w;
    }
  }
  const float* bp0 = b0 + bn + tc;
  const float* bp1 = b1 + bn + tc;
#pragma unroll
  for (int i = 0; i < 4; ++i) {
    float* cp = C + (size_t)(bm + tr + i) * N + bn + tc;
#pragma unroll
    for (int j = 0; j < 4; ++j) cp[j] = acc[i][j] + bp0[j] + bp1[j];
  }
}

__global__ __launch_bounds__(256)
void lstm_step(const float* __restrict__ gx, long long gxstride,
               const float* __restrict__ whh,
               const float* __restrict__ hprev, long long pstride,
               float* __restrict__ hnext, long long nstride,
               float* __restrict__ cbuf) {
  __shared__ float hs[32][16];
  __shared__ float wsm[32][4][32];
  const int tid = threadIdx.x;
  const int jt = blockIdx.x << 5;
  const int bm = blockIdx.y << 4;
  const int col = tid & 31;
  const int rp = (tid >> 5) << 1;
  const int hr = tid >> 4;
  const int hk = (tid & 15) << 1;
  const int wrow = tid & 127;
  const int wg = wrow >> 5;
  const int wc = wrow & 31;
  const int wk = (tid >> 7) << 4;
  const float* wbase = whh + (size_t)(wg * HH + jt + wc) * HH + wk;
  const float* hbase = hprev + (size_t)(bm + hr) * pstride + hk;

  float acc[4][2] = {};
  for (int k0 = 0; k0 < HH; k0 += 32) {
    const float2 hv = *(const float2*)(hbase + k0);
    const float4 wv0 = *(const float4*)(wbase + k0);
    const float4 wv1 = *(const float4*)(wbase + k0 + 4);
    const float4 wv2 = *(const float4*)(wbase + k0 + 8);
    const float4 wv3 = *(const float4*)(wbase + k0 + 12);
    __syncthreads();
    hs[hk][hr] = hv.x; hs[hk + 1][hr] = hv.y;
    {
      const float wvv[16] = {wv0.x, wv0.y, wv0.z, wv0.w, wv1.x, wv1.y, wv1.z, wv1.w,
                             wv2.x, wv2.y, wv2.z, wv2.w, wv3.x, wv3.y, wv3.z, wv3.w};
#pragma unroll
      for (int i = 0; i < 16; ++i) wsm[wk + i][wg][wc] = wvv[i];
    }
    __syncthreads();
#pragma unroll
    for (int k = 0; k < 32; ++k) {
      const float2 a = *(const float2*)&hs[k][rp];
      const float wi = wsm[k][0][col];
      const float wf = wsm[k][1][col];
      const float wg_ = wsm[k][2][col];
      const float wo = wsm[k][3][col];
      acc[0][0] += a.x * wi;  acc[0][1] += a.y * wi;
      acc[1][0] += a.x * wf;  acc[1][1] += a.y * wf;
      acc[2][0] += a.x * wg_; acc[2][1] += a.y * wg_;
      acc[3][0] += a.x * wo;  acc[3][1] += a.y * wo;
    }
  }
#pragma unroll
  for (int rr = 0; rr < 2; ++rr) {
    const int b = bm + rp + rr;
    const int j = jt + col;
    const size_t gxo = (size_t)b * gxstride + j;
    const float gi = acc[0][rr] + gx[gxo];
    const float gf = acc[1][rr] + gx[gxo + HH];
    const float gg = acc[2][rr] + gx[gxo + 2 * HH];
    const float go = acc[3][rr] + gx[gxo + 3 * HH];
    const float si = 1.f / (1.f + expf(-gi));
    const float sf = 1.f / (1.f + expf(-gf));
    const float so = 1.f / (1.f + expf(-go));
    const size_t cidx = (size_t)b * HH + j;
    const float cn = sf * cbuf[cidx] + si * tanhf(gg);
    cbuf[cidx] = cn;
    hnext[(size_t)b * nstride + j] = so * tanhf(cn);
  }
}

__global__ __launch_bounds__(256)
void fc_kernel(const float* __restrict__ hlast, const float* __restrict__ fcw,
               const float* __restrict__ fcb, float* __restrict__ out) {
  const int gw = (int)((blockIdx.x * 256 + threadIdx.x) >> 6);
  const int lane = threadIdx.x & 63;
  const int b = gw / CO;
  const int n = gw - b * CO;
  const float* hp = hlast + (size_t)b * HH;
  const float* wp = fcw + (size_t)n * HH;
  float s = 0.f;
  for (int k = lane; k < HH; k += 64) s += hp[k] * wp[k];
#pragma unroll
  for (int off = 32; off; off >>= 1) s += __shfl_down(s, off);
  if (lane == 0) out[b * CO + n] = s + fcb[n];
}

// ==================================================================
extern "C" void kernel_launch(void* const* d_in, const int* in_sizes, int n_in,
                              void* d_out, int out_size, void* d_ws, size_t ws_size,
                              hipStream_t stream) {
  const float* x    = (const float*)d_in[0];
  const float* wih0 = (const float*)d_in[1];
  const float* whh0 = (const float*)d_in[2];
  const float* bih0 = (const float*)d_in[3];
  const float* bhh0 = (const float*)d_in[4];
  const float* wih1 = (const float*)d_in[5];
  const float* whh1 = (const float*)d_in[6];
  const float* bih1 = (const float*)d_in[7];
  const float* bhh1 = (const float*)d_in[8];
  const float* fcw  = (const float*)d_in[9];
  const float* fcb  = (const float*)d_in[10];
  float* out = (float*)d_out;

  // ---- MFMA-path workspace ----
  const size_t pk0B  = (size_t)256 * 48 * 1024 * 2;   // 25,165,824 B
  const size_t pk1B  = (size_t)256 * 64 * 1024 * 2;   // 33,554,432 B
  const size_t slotB = 2 * (size_t)BB * HH * 2;       // 524,288 B (hi+lo)
  const size_t cB    = (size_t)BB * HH * 4;           // 524,288 B
  const size_t needB = pk0B + pk1B + 4 * slotB + 2 * cB;  // 61,865,984 B

  if (needB <= ws_size) {
    char* p = (char*)d_ws;
    unsigned short* pk0  = (unsigned short*)p; p += pk0B;
    unsigned short* pk1  = (unsigned short*)p; p += pk1B;
    unsigned short* h0s0 = (unsigned short*)p; p += slotB;
    unsigned short* h1s0 = (unsigned short*)p; p += slotB;
    char* zblock = p;                         // h0s1, h1s1, c0, c1 (zeroed)
    unsigned short* h0s1 = (unsigned short*)p; p += slotB;
    unsigned short* h1s1 = (unsigned short*)p; p += slotB;
    float* c0 = (float*)p; p += cB;
    float* c1 = (float*)p; p += cB;

    hipMemsetAsync(zblock, 0, 2 * slotB + 2 * cB, stream);

    pack_w2<<<dim3((256 * 48 * 64) / 256), 256, 0, stream>>>(whh0, wih0, pk0, HH, DD);
    pack_w2<<<dim3((256 * 64 * 64) / 256), 256, 0, stream>>>(whh1, wih1, pk1, HH, HH);

    for (int t = 0; t <= TT; ++t) {
      step_dual<<<dim3(256), 512, 0, stream>>>(t, x, pk0, pk1,
                                               h0s0, h0s1, h1s0, h1s1,
                                               bih0, bhh0, bih1, bhh1, c0, c1);
    }

    // final u = 255 (odd) wrote slot[1] = h1s1
    fc_hilo<<<dim3((BB * CO * 64) / 256), 256, 0, stream>>>(h1s1, h1s1 + LOOFF,
                                                            fcw, fcb, out);
    return;
  }

  // ---------------- fallback fp32 path ----------------
  {
    int Tc2 = 64, lt2 = 6;
    while (Tc2 > 1) {
      size_t need = ((size_t)655360 * (size_t)Tc2 + 4u * 131072u + 1024u) * 4u;
      if (need <= ws_size) break;
      Tc2 >>= 1; --lt2;
    }
    float* ws  = (float*)d_ws;
    float* gxc = ws;
    float* hc  = gxc + (size_t)BB * Tc2 * G4H;
    float* c0  = hc + (size_t)BB * Tc2 * HH;
    float* c1  = c0 + (size_t)BB * HH;
    float* h2a = c1 + (size_t)BB * HH;
    float* h2b = h2a + (size_t)BB * HH;
    float* zb  = h2b + (size_t)BB * HH;

    hipMemsetAsync(zb, 0, HH * sizeof(float), stream);
    hipMemsetAsync(c0, 0, (size_t)BB * HH * sizeof(float), stream);
    hipMemsetAsync(c1, 0, (size_t)BB * HH * sizeof(float), stream);

    const dim3 gGemm(G4H / 64, (BB * Tc2) / 64);
    const dim3 gStep(HH / 32, BB / 16);
    const long long gxs = (long long)Tc2 * G4H;
    const long long hcs = (long long)Tc2 * HH;

    const int nChunks = TT / Tc2;
    for (int ci = 0; ci < nChunks; ++ci) {
      const int t0 = ci * Tc2;
      gemm_bias<<<gGemm, 256, 0, stream>>>(x + (size_t)t0 * DD, (long long)TT * DD,
                                           (long long)DD, lt2, wih0, bih0, bhh0,
                                           gxc, G4H, DD);
      for (int tl = 0; tl < Tc2; ++tl) {
        const int t = t0 + tl;
        const float* hprev;
        long long ps;
        if (t == 0) { hprev = zb; ps = 0; }
        else {
          const int ptl = (tl == 0) ? (Tc2 - 1) : (tl - 1);
          hprev = hc + (size_t)ptl * HH; ps = hcs;
        }
        lstm_step<<<gStep, 256, 0, stream>>>(gxc + (size_t)tl * G4H, gxs, whh0,
                                             hprev, ps, hc + (size_t)tl * HH, hcs, c0);
      }
      gemm_bias<<<gGemm, 256, 0, stream>>>(hc, hcs, (long long)HH, lt2,
                                           wih1, bih1, bhh1, gxc, G4H, HH);
      for (int tl = 0; tl < Tc2; ++tl) {
        const int t = t0 + tl;
        const float* hprev;
        long long ps;
        if (t == 0) { hprev = zb; ps = 0; }
        else { hprev = ((t - 1) & 1) ? h2b : h2a; ps = HH; }
        float* hnext = (t & 1) ? h2b : h2a;
        lstm_step<<<gStep, 256, 0, stream>>>(gxc + (size_t)tl * G4H, gxs, whh1,
                                             hprev, ps, hnext, HH, c1);
      }
    }
    fc_kernel<<<dim3((BB * CO * 64) / 256), 256, 0, stream>>>(h2b, fcw, fcb, out);
  }
}